// Round 10
// baseline (696.954 us; speedup 1.0000x reference)
//
#include <hip/hip_runtime.h>

// Problem constants (N=1)
constexpr int W_ = 160;   // input W (x), output dim 1
constexpr int H_ = 192;   // input H (y), output dim 2
constexpr int D_ = 64;    // input D (z), output dim 4 (innermost)
constexpr int C_ = 32;
constexpr int HW_  = H_ * W_;          // 30720
constexpr int DHWi = D_ * HW_;         // 1966080
constexpr int CD   = C_ * D_;          // 2048

// R9 post-mortem: two 32-reg P stages + ~30 constants > the 64 VGPR the
// allocator settled on -> ONE batch live + small spill (WRITE +42 MB); the
// ILP pipeline was defeated by the register allocator for the third time.
// R10: get latency hiding from TLP instead. Single change vs R7 (353 us):
// remove the 36 KB residency throttle (its L2-window purpose is obsolete --
// FETCH=100 MB proved reads are cache-resident) and raise occupancy
// 4 -> 8 blocks/CU via __launch_bounds__(256, 8) (VGPR cap 64; R7 used 40).
// During one wave's single long post-batch wait, 7 other waves issue their
// ~350-cycle VALU blocks -> VALU fill ~2x. (R1's "more waves = null" was on
// the serialized 16-round-trip convoy structure; it does not transfer to the
// one-wait-per-iteration batched structure.)
// Keep frozen: L2 phase schedule, x-pair dwordx2 gathers, mega value-pin
// (noalias-proof) + sched_barrier, direct f4 NT stores, zero barriers.
constexpr int TW = 32, TH = 12, TD = 16;
constexpr int NWT = W_ / TW;             // 5
constexpr int NHT = H_ / TH;             // 16
constexpr int NDT = D_ / TD;             // 4
constexpr int QPP = NWT * NHT;           // 80 blocks per phase
constexpr int CPX = C_ / 8;              // 4 channels per XCD
constexpr int NPH = CPX * NDT;           // 16 phases per XCD

typedef float f4_t __attribute__((ext_vector_type(4)));
typedef float f2_t __attribute__((ext_vector_type(2)));

__global__ void __launch_bounds__(256, 8)
affine_grid_sample_kernel(const float* __restrict__ inp,
                          const float* __restrict__ th,
                          float* __restrict__ out)
{
    const int t   = threadIdx.x;
    const int bid = blockIdx.x;
    const int xcd = bid & 7;             // XCD id (dispatch round-robin)
    int r = bid >> 3;                    // 0..1279 within XCD, dispatch order
    const int phase = r / QPP;           // 0..15 slowest: one (c,dt) slab at a time
    const int q     = r - phase * QPP;
    const int c  = xcd * CPX + (phase >> 2);
    const int dt = phase & 3;            // dt fastest -> consecutive phases share z-halo
    const int hs = q / NWT;
    const int wt = q - hs * NWT;
    const int w0 = wt * TW, h0 = hs * TH, d0 = dt * TD;

    const float th0=th[0], th1=th[1], th2 =th[2],  th3 =th[3];
    const float th4=th[4], th5=th[5], th6 =th[6],  th7 =th[7];
    const float th8=th[8], th9=th[9], th10=th[10], th11=th[11];

    const float* __restrict__ pc = inp + (size_t)c * DHWi;

    // lane map: wave = (wl:16) x (dq:4) -> full 64B store segments per wave.
    const int wl = t & 15;               // w within 16-group
    const int dq = (t >> 4) & 3;         // d-quad: owns d0+4dq .. d0+4dq+3
    const int wh = (t >> 6) & 1;         // w-half of the 32-wide tile
    const int hp = t >> 7;               // h parity (threads 128..255 take odd hh)
    const int w  = w0 + wh * 16 + wl;
    const float xx = fmaf((float)w, 2.0f / (W_ - 1), -1.0f);

    // per-thread z-constants for its 4 d's
    float kzx[4], kzy[4], kzz[4];
    #pragma unroll
    for (int k = 0; k < 4; ++k) {
        const int d = d0 + 4 * dq + k;
        const float zz = fmaf((float)d, 2.0f / (D_ - 1), -1.0f);
        kzx[k] = fmaf(th2,  zz, th3);
        kzy[k] = fmaf(th6,  zz, th7);
        kzz[k] = fmaf(th10, zz, th11);
    }

    float* const ob = out + ((size_t)w * H_ + h0) * CD + (size_t)c * D_ + d0 + 4 * dq;

    #pragma unroll 1
    for (int hh = hp; hh < TH; hh += 2) {
        const float yy = fmaf((float)(h0 + hh), 2.0f / (H_ - 1), -1.0f);

        // ---- per point: 4 row offsets (x-pair base) + shuffled pair weights ----
        unsigned off[4][4];
        float wA[4], wB[4], v0a[4], v1a[4], s0a[4], s1a[4];
        #pragma unroll
        for (int k = 0; k < 4; ++k) {
            const float px = (fmaf(th0, xx, fmaf(th1, yy, kzx[k])) + 1.0f) * (0.5f * (W_ - 1));
            const float py = (fmaf(th4, xx, fmaf(th5, yy, kzy[k])) + 1.0f) * (0.5f * (H_ - 1));
            const float pz = (fmaf(th8, xx, fmaf(th9, yy, kzz[k])) + 1.0f) * (0.5f * (D_ - 1));
            const float fx = floorf(px), fy = floorf(py), fz = floorf(pz);
            const int ix0 = (int)fx, iy0 = (int)fy, iz0 = (int)fz;
            const float wx = px - fx, wy = py - fy, wz = pz - fz;
            // zeros-padding: per-axis weight of any OOB corner is zeroed
            const float u0r = ((unsigned)ix0       < (unsigned)W_) ? (1.0f - wx) : 0.0f;
            const float u1r = ((unsigned)(ix0 + 1) < (unsigned)W_) ? wx          : 0.0f;
            v0a[k] = ((unsigned)iy0       < (unsigned)H_) ? (1.0f - wy) : 0.0f;
            v1a[k] = ((unsigned)(iy0 + 1) < (unsigned)H_) ? wy          : 0.0f;
            s0a[k] = ((unsigned)iz0       < (unsigned)D_) ? (1.0f - wz) : 0.0f;
            s1a[k] = ((unsigned)(iz0 + 1) < (unsigned)D_) ? wz          : 0.0f;
            // pair P = (v[e], v[e+1]) with e = clamp(ix0, 0, W-2). Exact cases:
            //   ix0 in [0,W-2] : (wA,wB) = (u0r,u1r)           P=(x0,x1)
            //   ix0 == -1     : (u1r, 0)  -- x1 is v[0] = P.a
            //   ix0 == W-1    : (0, u0r)  -- x0 is v[W-1] = P.b
            //   else          : u0r=u1r=0 already
            float a = u0r, b = u1r;
            if (ix0 == -1)     { a = u1r; b = 0.0f; }
            if (ix0 == W_ - 1) { a = 0.0f; b = u0r; }
            wA[k] = a; wB[k] = b;
            const int e = min(max(ix0, 0), W_ - 2);
            const int cy0 = min(max(iy0,     0), H_ - 1);
            const int cy1 = min(max(iy0 + 1, 0), H_ - 1);
            const int cz0 = min(max(iz0,     0), D_ - 1);
            const int cz1 = min(max(iz0 + 1, 0), D_ - 1);
            off[k][0] = (unsigned)(cz0 * HW_ + cy0 * W_ + e);
            off[k][1] = (unsigned)(cz0 * HW_ + cy1 * W_ + e);
            off[k][2] = (unsigned)(cz1 * HW_ + cy0 * W_ + e);
            off[k][3] = (unsigned)(cz1 * HW_ + cy1 * W_ + e);
        }

        // ---- issue ALL 16 pair-loads as one batch ----
        f2_t P[4][4];
        #pragma unroll
        for (int k = 0; k < 4; ++k)
            #pragma unroll
            for (int j = 0; j < 4; ++j)
                __builtin_memcpy(&P[k][j], pc + off[k][j], 8);  // 8B load, 4B-aligned

        // Pin ALL results live at one point: forces back-to-back issue + a single
        // vmcnt wait. (Value-level pin -- cannot be defeated by noalias AA.)
        // sched_barrier stops blends hoisting above.
        asm volatile("" ::
            "v"(P[0][0]), "v"(P[0][1]), "v"(P[0][2]), "v"(P[0][3]),
            "v"(P[1][0]), "v"(P[1][1]), "v"(P[1][2]), "v"(P[1][3]),
            "v"(P[2][0]), "v"(P[2][1]), "v"(P[2][2]), "v"(P[2][3]),
            "v"(P[3][0]), "v"(P[3][1]), "v"(P[3][2]), "v"(P[3][3]));
        __builtin_amdgcn_sched_barrier(0);

        // ---- blend + direct full-width store (wave covers 16 w x 64B) ----
        f4_t val;
        #pragma unroll
        for (int k = 0; k < 4; ++k) {
            const float x00 = wA[k] * P[k][0][0] + wB[k] * P[k][0][1];
            const float x01 = wA[k] * P[k][1][0] + wB[k] * P[k][1][1];
            const float x10 = wA[k] * P[k][2][0] + wB[k] * P[k][2][1];
            const float x11 = wA[k] * P[k][3][0] + wB[k] * P[k][3][1];
            const float e0 = v0a[k] * x00 + v1a[k] * x01;
            const float e1 = v0a[k] * x10 + v1a[k] * x11;
            val[k] = s0a[k] * e0 + s1a[k] * e1;
        }
        // output is write-once streaming: non-temporal
        __builtin_nontemporal_store(val, (f4_t*)(ob + (size_t)hh * CD));
    }
}

extern "C" void kernel_launch(void* const* d_in, const int* in_sizes, int n_in,
                              void* d_out, int out_size, void* d_ws, size_t ws_size,
                              hipStream_t stream)
{
    const float* inp = (const float*)d_in[0];   // [1,32,64,192,160] fp32
    const float* th  = (const float*)d_in[1];   // 12 fp32
    float* out = (float*)d_out;                 // [1,160,192,32,64] fp32

    hipLaunchKernelGGL(affine_grid_sample_kernel, dim3(8 * NPH * QPP), dim3(256),
                       0, stream, inp, th, out);
}

// Round 11
// 644.044 us; speedup vs baseline: 1.0822x; 1.0822x over previous
//
#include <hip/hip_runtime.h>

// Problem constants (N=1)
constexpr int W_ = 160;   // input W (x), output dim 1
constexpr int H_ = 192;   // input H (y), output dim 2
constexpr int D_ = 64;    // input D (z), output dim 4 (innermost)
constexpr int C_ = 32;
constexpr int HW_  = H_ * W_;          // 30720
constexpr int DHWi = D_ * HW_;         // 1966080
constexpr int CD   = C_ * D_;          // 2048

// R10 post-mortem: __launch_bounds__(256,8) forced VGPR 40->32, which broke the
// pinned 16-load batch (re-serialized + spilled: WRITE 246->328 MB) while
// occupancy hit 86% -- the high-occupancy experiment never ran on the good
// inner loop. Little's-law fit of R7: 256 outstanding req/CU at ~220cy (L2)
// = 1.16 req/cyc = the measured 848K cycles -> R7 is CONCURRENCY-bound at one
// batch/wave. R11 discriminator: R7's exact codegen (VGPR cap 128 via
// launch_bounds(256,4) -> compiler unchanged, VGPR=40) with residency raised
// to 8 blocks/CU by DELETING the vestigial LDS throttle (hardware packs 8:
// 8 waves/SIMD x 40 VGPR = 320 <= 512).
//   dur <= 300 us  -> latency/concurrency model: keep raising TLP.
//   dur >= 330 us  -> TCP request-service cap confirmed (with R1+R10) ->
//                     R12 = dense-stage + LDS-gather redesign.
// Keep frozen: L2 phase schedule, x-pair dwordx2 gathers, mega value-pin
// (noalias-proof) + sched_barrier, direct f4 NT stores, zero barriers.
constexpr int TW = 32, TH = 12, TD = 16;
constexpr int NWT = W_ / TW;             // 5
constexpr int NHT = H_ / TH;             // 16
constexpr int NDT = D_ / TD;             // 4
constexpr int QPP = NWT * NHT;           // 80 blocks per phase
constexpr int CPX = C_ / 8;              // 4 channels per XCD
constexpr int NPH = CPX * NDT;           // 16 phases per XCD

typedef float f4_t __attribute__((ext_vector_type(4)));
typedef float f2_t __attribute__((ext_vector_type(2)));

__global__ void __launch_bounds__(256, 4)
affine_grid_sample_kernel(const float* __restrict__ inp,
                          const float* __restrict__ th,
                          float* __restrict__ out)
{
    const int t   = threadIdx.x;
    const int bid = blockIdx.x;
    const int xcd = bid & 7;             // XCD id (dispatch round-robin)
    int r = bid >> 3;                    // 0..1279 within XCD, dispatch order
    const int phase = r / QPP;           // 0..15 slowest: one (c,dt) slab at a time
    const int q     = r - phase * QPP;
    const int c  = xcd * CPX + (phase >> 2);
    const int dt = phase & 3;            // dt fastest -> consecutive phases share z-halo
    const int hs = q / NWT;
    const int wt = q - hs * NWT;
    const int w0 = wt * TW, h0 = hs * TH, d0 = dt * TD;

    const float th0=th[0], th1=th[1], th2 =th[2],  th3 =th[3];
    const float th4=th[4], th5=th[5], th6 =th[6],  th7 =th[7];
    const float th8=th[8], th9=th[9], th10=th[10], th11=th[11];

    const float* __restrict__ pc = inp + (size_t)c * DHWi;

    // lane map: wave = (wl:16) x (dq:4) -> full 64B store segments per wave.
    const int wl = t & 15;               // w within 16-group
    const int dq = (t >> 4) & 3;         // d-quad: owns d0+4dq .. d0+4dq+3
    const int wh = (t >> 6) & 1;         // w-half of the 32-wide tile
    const int hp = t >> 7;               // h parity (threads 128..255 take odd hh)
    const int w  = w0 + wh * 16 + wl;
    const float xx = fmaf((float)w, 2.0f / (W_ - 1), -1.0f);

    // per-thread z-constants for its 4 d's
    float kzx[4], kzy[4], kzz[4];
    #pragma unroll
    for (int k = 0; k < 4; ++k) {
        const int d = d0 + 4 * dq + k;
        const float zz = fmaf((float)d, 2.0f / (D_ - 1), -1.0f);
        kzx[k] = fmaf(th2,  zz, th3);
        kzy[k] = fmaf(th6,  zz, th7);
        kzz[k] = fmaf(th10, zz, th11);
    }

    float* const ob = out + ((size_t)w * H_ + h0) * CD + (size_t)c * D_ + d0 + 4 * dq;

    #pragma unroll 1
    for (int hh = hp; hh < TH; hh += 2) {
        const float yy = fmaf((float)(h0 + hh), 2.0f / (H_ - 1), -1.0f);

        // ---- per point: 4 row offsets (x-pair base) + shuffled pair weights ----
        unsigned off[4][4];
        float wA[4], wB[4], v0a[4], v1a[4], s0a[4], s1a[4];
        #pragma unroll
        for (int k = 0; k < 4; ++k) {
            const float px = (fmaf(th0, xx, fmaf(th1, yy, kzx[k])) + 1.0f) * (0.5f * (W_ - 1));
            const float py = (fmaf(th4, xx, fmaf(th5, yy, kzy[k])) + 1.0f) * (0.5f * (H_ - 1));
            const float pz = (fmaf(th8, xx, fmaf(th9, yy, kzz[k])) + 1.0f) * (0.5f * (D_ - 1));
            const float fx = floorf(px), fy = floorf(py), fz = floorf(pz);
            const int ix0 = (int)fx, iy0 = (int)fy, iz0 = (int)fz;
            const float wx = px - fx, wy = py - fy, wz = pz - fz;
            // zeros-padding: per-axis weight of any OOB corner is zeroed
            const float u0r = ((unsigned)ix0       < (unsigned)W_) ? (1.0f - wx) : 0.0f;
            const float u1r = ((unsigned)(ix0 + 1) < (unsigned)W_) ? wx          : 0.0f;
            v0a[k] = ((unsigned)iy0       < (unsigned)H_) ? (1.0f - wy) : 0.0f;
            v1a[k] = ((unsigned)(iy0 + 1) < (unsigned)H_) ? wy          : 0.0f;
            s0a[k] = ((unsigned)iz0       < (unsigned)D_) ? (1.0f - wz) : 0.0f;
            s1a[k] = ((unsigned)(iz0 + 1) < (unsigned)D_) ? wz          : 0.0f;
            // pair P = (v[e], v[e+1]) with e = clamp(ix0, 0, W-2). Exact cases:
            //   ix0 in [0,W-2] : (wA,wB) = (u0r,u1r)           P=(x0,x1)
            //   ix0 == -1     : (u1r, 0)  -- x1 is v[0] = P.a
            //   ix0 == W-1    : (0, u0r)  -- x0 is v[W-1] = P.b
            //   else          : u0r=u1r=0 already
            float a = u0r, b = u1r;
            if (ix0 == -1)     { a = u1r; b = 0.0f; }
            if (ix0 == W_ - 1) { a = 0.0f; b = u0r; }
            wA[k] = a; wB[k] = b;
            const int e = min(max(ix0, 0), W_ - 2);
            const int cy0 = min(max(iy0,     0), H_ - 1);
            const int cy1 = min(max(iy0 + 1, 0), H_ - 1);
            const int cz0 = min(max(iz0,     0), D_ - 1);
            const int cz1 = min(max(iz0 + 1, 0), D_ - 1);
            off[k][0] = (unsigned)(cz0 * HW_ + cy0 * W_ + e);
            off[k][1] = (unsigned)(cz0 * HW_ + cy1 * W_ + e);
            off[k][2] = (unsigned)(cz1 * HW_ + cy0 * W_ + e);
            off[k][3] = (unsigned)(cz1 * HW_ + cy1 * W_ + e);
        }

        // ---- issue ALL 16 pair-loads as one batch ----
        f2_t P[4][4];
        #pragma unroll
        for (int k = 0; k < 4; ++k)
            #pragma unroll
            for (int j = 0; j < 4; ++j)
                __builtin_memcpy(&P[k][j], pc + off[k][j], 8);  // 8B load, 4B-aligned

        // Pin ALL results live at one point: forces back-to-back issue + a single
        // vmcnt wait. (Value-level pin -- cannot be defeated by noalias AA.)
        // sched_barrier stops blends hoisting above.
        asm volatile("" ::
            "v"(P[0][0]), "v"(P[0][1]), "v"(P[0][2]), "v"(P[0][3]),
            "v"(P[1][0]), "v"(P[1][1]), "v"(P[1][2]), "v"(P[1][3]),
            "v"(P[2][0]), "v"(P[2][1]), "v"(P[2][2]), "v"(P[2][3]),
            "v"(P[3][0]), "v"(P[3][1]), "v"(P[3][2]), "v"(P[3][3]));
        __builtin_amdgcn_sched_barrier(0);

        // ---- blend + direct full-width store (wave covers 16 w x 64B) ----
        f4_t val;
        #pragma unroll
        for (int k = 0; k < 4; ++k) {
            const float x00 = wA[k] * P[k][0][0] + wB[k] * P[k][0][1];
            const float x01 = wA[k] * P[k][1][0] + wB[k] * P[k][1][1];
            const float x10 = wA[k] * P[k][2][0] + wB[k] * P[k][2][1];
            const float x11 = wA[k] * P[k][3][0] + wB[k] * P[k][3][1];
            const float e0 = v0a[k] * x00 + v1a[k] * x01;
            const float e1 = v0a[k] * x10 + v1a[k] * x11;
            val[k] = s0a[k] * e0 + s1a[k] * e1;
        }
        // output is write-once streaming: non-temporal
        __builtin_nontemporal_store(val, (f4_t*)(ob + (size_t)hh * CD));
    }
}

extern "C" void kernel_launch(void* const* d_in, const int* in_sizes, int n_in,
                              void* d_out, int out_size, void* d_ws, size_t ws_size,
                              hipStream_t stream)
{
    const float* inp = (const float*)d_in[0];   // [1,32,64,192,160] fp32
    const float* th  = (const float*)d_in[1];   // 12 fp32
    float* out = (float*)d_out;                 // [1,160,192,32,64] fp32

    hipLaunchKernelGGL(affine_grid_sample_kernel, dim3(8 * NPH * QPP), dim3(256),
                       0, stream, inp, th, out);
}